// Round 1
// baseline (52.030 us; speedup 1.0000x reference)
//
#include <hip/hip_runtime.h>
#include <hip/hip_bf16.h>

// Outer_14173392076867: pairwise-delta attention + MLP head, MI355X gfx950.
// K0: fc1_w f32->bf16            (ws)
// K1: per-(n,h) dX -> MFMA GEMMs -> att bf16 (ws)
// K2: split-K bf16 MFMA GEMM att @ fc1_w^T -> partials f32 (ws)
// K3: reduce partials + bias + silu + fc2 -> out[256]

typedef __attribute__((ext_vector_type(8))) short short8;
typedef __attribute__((ext_vector_type(4))) float f32x4;
typedef __attribute__((ext_vector_type(4))) unsigned short u16x4;

#define PP 64
#define TT 3
#define DD 64
#define PADW 88          // 64 + 24 ushorts -> 176B row stride: 16B-aligned, 2-way banks
#define K2_SPLITS 128    // K-chunk = 32768/128 = 256
#define KTOT 32768L

__device__ __forceinline__ unsigned short f2b(float x) {
  union { float f; unsigned int u; } v; v.f = x;
  return (unsigned short)((v.u + 0x7FFFu + ((v.u >> 16) & 1u)) >> 16);
}

// ---------------- K0: convert fc1_w (2,097,152 f32) to bf16 ----------------
__global__ __launch_bounds__(256)
void k_cvt_w(const float* __restrict__ in, unsigned short* __restrict__ out) {
  const int i = (blockIdx.x * 256 + threadIdx.x) * 4;
  f32x4 v = *(const f32x4*)(in + i);
  u16x4 o;
#pragma unroll
  for (int e = 0; e < 4; ++e) o[e] = f2b(v[e]);
  *(u16x4*)(out + i) = o;
}

// ---------------- K1: att[n,h,i,d] ----------------
// grid = 2048 (n*8+h), block = 256 (4 waves). Each wave owns a 16-row stripe
// of the 64x64 output; mfma_f32_16x16x32_bf16, K=64 over j.
__global__ __launch_bounds__(256, 2)
void k_att(const float* __restrict__ X, const float* __restrict__ Wl_g,
           const float* __restrict__ Wr_g, unsigned short* __restrict__ att) {
  __shared__ float xs[TT][PP];
  __shared__ __align__(16) unsigned short wl[DD][PADW];  // [d][j] (transposed)
  __shared__ __align__(16) unsigned short wr[DD][PADW];
  __shared__ __align__(16) unsigned short dx[PP][PADW];  // [i][j]

  const int blk  = blockIdx.x;       // n*8 + h
  const int h    = blk & 7;
  const int tid  = threadIdx.x;
  const int lane = tid & 63;
  const int w    = tid >> 6;         // wave id 0..3
  const int c0   = lane & 15;
  const int ks   = lane >> 4;        // 0..3

  // X slice: 192 contiguous floats, layout [i][t] -> store xs[t][i]
  if (tid < PP * TT) {
    float v = X[blk * (PP * TT) + tid];
    int i = tid / TT, t = tid - i * TT;
    xs[t][i] = v;
  }
  // W slices (16KB each, L2-resident across the 256 blocks sharing h),
  // coalesced global read [j][d], transposed bf16 store [d][j].
  const float* wlg = Wl_g + h * (PP * DD);
  const float* wrg = Wr_g + h * (PP * DD);
  for (int e = tid; e < PP * DD; e += 256) {
    int j = e >> 6, d = e & 63;
    wl[d][j] = f2b(wlg[e]);
    wr[d][j] = f2b(wrg[e]);
  }
  __syncthreads();

  // B fragments (t-invariant): B[k=j][n=d], lane: col=c0(+16cb), k=ks*8+jj(+32kb)
  short8 bl[4][2], br[4][2];
#pragma unroll
  for (int cb = 0; cb < 4; ++cb)
#pragma unroll
    for (int kb = 0; kb < 2; ++kb) {
      const int d = c0 + 16 * cb;
      const int j0 = ks * 8 + 32 * kb;
      bl[cb][kb] = *(const short8*)&wl[d][j0];
      br[cb][kb] = *(const short8*)&wr[d][j0];
    }

  f32x4 acc[4];
#pragma unroll
  for (int cb = 0; cb < 4; ++cb) {
    acc[cb][0] = 0.f; acc[cb][1] = 0.f; acc[cb][2] = 0.f; acc[cb][3] = 0.f;
  }

  const int di  = tid >> 2;          // dX row this thread fills
  const int dj0 = (tid & 3) << 4;    // 16-col chunk

  for (int t = 0; t < TT; ++t) {
    // dX[i,j] = delta * rsqrt(delta^2+eps) * exp(-dist); 16 elems/thread
    const float xi = xs[t][di];
#pragma unroll
    for (int jj = 0; jj < 16; jj += 2) {
      float d0 = xi - xs[t][dj0 + jj];
      float d1 = xi - xs[t][dj0 + jj + 1];
      float s0 = d0 * d0 + 1e-5f;
      float s1 = d1 * d1 + 1e-5f;
      float i0 = rsqrtf(s0), i1 = rsqrtf(s1);
      float e0 = __expf(-(s0 * i0));
      float e1 = __expf(-(s1 * i1));
      unsigned int pk = (unsigned int)f2b(d0 * i0 * e0) |
                        ((unsigned int)f2b(d1 * i1 * e1) << 16);
      *(unsigned int*)&dx[di][dj0 + jj] = pk;
    }
    __syncthreads();

    // A frags: row = 16w + c0, k = ks*8 (+32)
    short8 a0 = *(const short8*)&dx[16 * w + c0][ks * 8];
    short8 a1 = *(const short8*)&dx[16 * w + c0][ks * 8 + 32];
#pragma unroll
    for (int cb = 0; cb < 4; ++cb) {
      f32x4 xl; xl[0]=0.f; xl[1]=0.f; xl[2]=0.f; xl[3]=0.f;
      f32x4 xr; xr[0]=0.f; xr[1]=0.f; xr[2]=0.f; xr[3]=0.f;
      xl = __builtin_amdgcn_mfma_f32_16x16x32_bf16(a0, bl[cb][0], xl, 0, 0, 0);
      xl = __builtin_amdgcn_mfma_f32_16x16x32_bf16(a1, bl[cb][1], xl, 0, 0, 0);
      xr = __builtin_amdgcn_mfma_f32_16x16x32_bf16(a0, br[cb][0], xr, 0, 0, 0);
      xr = __builtin_amdgcn_mfma_f32_16x16x32_bf16(a1, br[cb][1], xr, 0, 0, 0);
      acc[cb] += xl * xr;            // att += Xl .* Xr   (reduce over t)
    }
    __syncthreads();
  }

  // C/D layout (m89-verified): col = lane&15, row = (lane>>4)*4 + reg
  unsigned short* ap = att + (size_t)blk * (PP * DD);
#pragma unroll
  for (int cb = 0; cb < 4; ++cb)
#pragma unroll
    for (int r = 0; r < 4; ++r) {
      int i = 16 * w + ks * 4 + r;
      int d = c0 + 16 * cb;
      ap[i * DD + d] = f2b(acc[cb][r]);
    }
}

// ---------------- K2: hdn partials = att @ fc1_w^T (split-K) ----------------
// grid = (4 m-tiles, 128 k-splits), block = 256. A,B both K-major bf16; frags
// loaded straight from global (lanes {l,l+16,l+32,l+48} cover 64B of one row).
__global__ __launch_bounds__(256, 2)
void k_fc1(const unsigned short* __restrict__ A, const unsigned short* __restrict__ Bw,
           float* __restrict__ partial) {
  const int mt   = blockIdx.x;
  const int sp   = blockIdx.y;
  const int tid  = threadIdx.x;
  const int lane = tid & 63;
  const int w    = tid >> 6;
  const int c0   = lane & 15;
  const int ks   = lane >> 4;

  const int row = mt * 64 + 16 * w + c0;
  const unsigned short* arow = A  + (long)row * KTOT + sp * 256 + ks * 8;
  const unsigned short* bb   = Bw + (long)c0  * KTOT + sp * 256 + ks * 8;

  f32x4 acc[4];
#pragma unroll
  for (int cb = 0; cb < 4; ++cb) {
    acc[cb][0] = 0.f; acc[cb][1] = 0.f; acc[cb][2] = 0.f; acc[cb][3] = 0.f;
  }

#pragma unroll
  for (int kk = 0; kk < 8; ++kk) {
    short8 a = *(const short8*)(arow + kk * 32);
#pragma unroll
    for (int cb = 0; cb < 4; ++cb) {
      short8 b = *(const short8*)(bb + (long)(16 * cb) * KTOT + kk * 32);
      acc[cb] = __builtin_amdgcn_mfma_f32_16x16x32_bf16(a, b, acc[cb], 0, 0, 0);
    }
  }

  float* pp = partial + ((long)sp * 256 + mt * 64 + 16 * w) * 64;
#pragma unroll
  for (int cb = 0; cb < 4; ++cb)
#pragma unroll
    for (int r = 0; r < 4; ++r)
      pp[(ks * 4 + r) * 64 + c0 + 16 * cb] = acc[cb][r];
}

// ---------------- K3: reduce + bias + silu + fc2 ----------------
// grid = 64, block = 256: one wave per n (lane = k).
__global__ __launch_bounds__(256)
void k_fc2(const float* __restrict__ partial, const float* __restrict__ fc1_b,
           const float* __restrict__ fc2_w, const float* __restrict__ fc2_b,
           float* __restrict__ out) {
  const int tid = threadIdx.x;
  const int n = blockIdx.x * 4 + (tid >> 6);
  const int k = tid & 63;
  float s = fc1_b[k];
#pragma unroll 8
  for (int sp = 0; sp < K2_SPLITS; ++sp)
    s += partial[((long)sp * 256 + n) * 64 + k];
  float g = s / (1.f + __expf(-s));   // silu
  float v = g * fc2_w[k];
#pragma unroll
  for (int off = 32; off > 0; off >>= 1)
    v += __shfl_xor(v, off, 64);
  if (k == 0) out[n] = v + fc2_b[0];
}

extern "C" void kernel_launch(void* const* d_in, const int* in_sizes, int n_in,
                              void* d_out, int out_size, void* d_ws, size_t ws_size,
                              hipStream_t stream) {
  const float* X    = (const float*)d_in[0];
  const float* Wl   = (const float*)d_in[1];
  const float* Wr   = (const float*)d_in[2];
  const float* fc1w = (const float*)d_in[3];
  const float* fc1b = (const float*)d_in[4];
  const float* fc2w = (const float*)d_in[5];
  const float* fc2b = (const float*)d_in[6];
  float* out = (float*)d_out;

  char* ws = (char*)d_ws;
  unsigned short* att     = (unsigned short*)(ws);               // 16,777,216 B
  unsigned short* w1b     = (unsigned short*)(ws + 16777216);    //  4,194,304 B
  float*          partial = (float*)(ws + 16777216 + 4194304);   //  8,388,608 B

  hipLaunchKernelGGL(k_cvt_w, dim3(2048), dim3(256), 0, stream, fc1w, w1b);
  hipLaunchKernelGGL(k_att,   dim3(2048), dim3(256), 0, stream, X, Wl, Wr, att);
  hipLaunchKernelGGL(k_fc1,   dim3(4, K2_SPLITS), dim3(256), 0, stream, att, w1b, partial);
  hipLaunchKernelGGL(k_fc2,   dim3(64), dim3(256), 0, stream, partial, fc1b, fc2w, fc2b, out);
}

// Round 2
// 41.239 us; speedup vs baseline: 1.2617x; 1.2617x over previous
//
#include <hip/hip_runtime.h>
#include <hip/hip_bf16.h>

// Outer_14173392076867 — fused pipeline, MI355X gfx950.
// K0: fc1_w f32->bf16 (k-major [64][32768]) into ws
// K1: fused per-(ih,h,ng): dX -> att half-tiles in LDS -> fc1 partial GEMM
//     streamed against w1b from L2. partial[16][256][64] f32 in ws.
// K2: reduce 16 partials + bias + silu + fc2 -> out[256]

typedef __attribute__((ext_vector_type(8))) short short8;
typedef __attribute__((ext_vector_type(4))) float f32x4;
typedef __attribute__((ext_vector_type(4))) unsigned short u16x4;

#define PADW 72      // LDS row pad (ushorts): 144B rows, 16B aligned
#define PADM 2056    // att row: 2048 + 8 -> 4112B rows, breaks bank alignment
#define KTOT 32768L

__device__ __forceinline__ unsigned short f2b(float x) {
  union { float f; unsigned int u; } v; v.f = x;
  return (unsigned short)((v.u + 0x7FFFu + ((v.u >> 16) & 1u)) >> 16);
}

// ---------------- K0: convert fc1_w (2,097,152 f32) to bf16 ----------------
__global__ __launch_bounds__(256)
void k_cvt_w(const float* __restrict__ in, unsigned short* __restrict__ out) {
  const int i = (blockIdx.x * 256 + threadIdx.x) * 4;
  f32x4 v = *(const f32x4*)(in + i);
  u16x4 o;
#pragma unroll
  for (int e = 0; e < 4; ++e) o[e] = f2b(v[e]);
  *(u16x4*)(out + i) = o;
}

// ---------------- K1: fused dX -> att (LDS) -> fc1 partial ----------------
// grid = 512: blk -> ih = blk&1 (i-half), h = (blk>>1)&7, ng = blk>>4 (8 n's).
// block = 256 (4 waves). Wave w: iw = w>>1 (16-row i-subtile), dw = w&1 (d-half).
__global__ __launch_bounds__(256, 2)
void k_fused(const float* __restrict__ X, const float* __restrict__ Wl_g,
             const float* __restrict__ Wr_g,
             const unsigned short* __restrict__ w1b,
             float* __restrict__ partial) {
  __shared__ float xs[8][3][64];                            //  6144 B
  __shared__ __align__(16) unsigned short wl[64][PADW];     //  9216 B
  __shared__ __align__(16) unsigned short wr[64][PADW];     //  9216 B
  __shared__ __align__(16) unsigned short dxs[3][32][PADW]; // 13824 B
  __shared__ __align__(16) unsigned short att_s[8][PADM];   // 32896 B
  __shared__ float red[4][8][64];                           //  8192 B  => 79488 B

  const int blk  = blockIdx.x;
  const int ih   = blk & 1;
  const int h    = (blk >> 1) & 7;
  const int ng   = blk >> 4;
  const int tid  = threadIdx.x;
  const int lane = tid & 63;
  const int w    = tid >> 6;
  const int c0   = lane & 15;
  const int ks   = lane >> 4;
  const int iw   = w >> 1;
  const int dw   = w & 1;

  // ---- W slices (per h): coalesced f32 read, transposed bf16 store [d][j]
  const float* wlg = Wl_g + h * 4096;
  const float* wrg = Wr_g + h * 4096;
  for (int e = tid; e < 4096; e += 256) {
    int j = e >> 6, d = e & 63;
    wl[d][j] = f2b(wlg[e]);
    wr[d][j] = f2b(wrg[e]);
  }
  // ---- X for all 8 n: [q][t][i] (1536 floats, coalesced)
  {
    const long xbase = ((long)ng * 64 + h) * 192;
#pragma unroll
    for (int r = 0; r < 6; ++r) {
      int e = tid + r * 256;
      int q = e / 192;
      int rem = e - q * 192;
      int i = rem / 3;
      int t = rem - i * 3;
      xs[q][t][i] = X[xbase + (long)q * 1536 + rem];
    }
  }
  __syncthreads();

  // ---- B fragments for the att GEMM (this wave's d-half), t-invariant
  short8 bl[2][2], br[2][2];
#pragma unroll
  for (int cb = 0; cb < 2; ++cb)
#pragma unroll
    for (int kb = 0; kb < 2; ++kb) {
      const int d = c0 + 16 * cb + 32 * dw;
      const int j0 = ks * 8 + 32 * kb;
      bl[cb][kb] = *(const short8*)&wl[d][j0];
      br[cb][kb] = *(const short8*)&wr[d][j0];
    }

  const int il  = tid >> 3;          // dX row (local, 0..31)
  const int jb  = (tid & 7) << 3;    // 8-col chunk

  for (int q = 0; q < 8; ++q) {
    if (q) __syncthreads();          // dxs overwrite vs prev A-reads
    // dX[i = ih*32+il][j] for 3 t's, 8 j's per thread
#pragma unroll
    for (int t = 0; t < 3; ++t) {
      const float xi = xs[q][t][ih * 32 + il];
#pragma unroll
      for (int jj = 0; jj < 8; jj += 2) {
        float d0 = xi - xs[q][t][jb + jj];
        float d1 = xi - xs[q][t][jb + jj + 1];
        float s0 = d0 * d0 + 1e-5f;
        float s1 = d1 * d1 + 1e-5f;
        float i0 = rsqrtf(s0), i1 = rsqrtf(s1);
        float e0 = __expf(-(s0 * i0));
        float e1 = __expf(-(s1 * i1));
        unsigned int pk = (unsigned int)f2b(d0 * i0 * e0) |
                          ((unsigned int)f2b(d1 * i1 * e1) << 16);
        *(unsigned int*)&dxs[t][il][jb + jj] = pk;
      }
    }
    __syncthreads();

    // att half-tile: wave computes [16 i x 32 d], K=64 over j, summed over t
    f32x4 acc[2];
#pragma unroll
    for (int cb = 0; cb < 2; ++cb) {
      acc[cb][0] = 0.f; acc[cb][1] = 0.f; acc[cb][2] = 0.f; acc[cb][3] = 0.f;
    }
#pragma unroll
    for (int t = 0; t < 3; ++t) {
      short8 a0 = *(const short8*)&dxs[t][iw * 16 + c0][ks * 8];
      short8 a1 = *(const short8*)&dxs[t][iw * 16 + c0][ks * 8 + 32];
#pragma unroll
      for (int cb = 0; cb < 2; ++cb) {
        f32x4 xl; xl[0]=0.f; xl[1]=0.f; xl[2]=0.f; xl[3]=0.f;
        f32x4 xr; xr[0]=0.f; xr[1]=0.f; xr[2]=0.f; xr[3]=0.f;
        xl = __builtin_amdgcn_mfma_f32_16x16x32_bf16(a0, bl[cb][0], xl, 0, 0, 0);
        xl = __builtin_amdgcn_mfma_f32_16x16x32_bf16(a1, bl[cb][1], xl, 0, 0, 0);
        xr = __builtin_amdgcn_mfma_f32_16x16x32_bf16(a0, br[cb][0], xr, 0, 0, 0);
        xr = __builtin_amdgcn_mfma_f32_16x16x32_bf16(a1, br[cb][1], xr, 0, 0, 0);
        acc[cb] += xl * xr;
      }
    }
    // store bf16 att tile: m-local = il2*64 + d
#pragma unroll
    for (int cb = 0; cb < 2; ++cb)
#pragma unroll
      for (int r = 0; r < 4; ++r) {
        int ro = iw * 16 + ks * 4 + r;
        int d = c0 + 16 * cb + 32 * dw;
        att_s[q][ro * 64 + d] = f2b(acc[cb][r]);
      }
  }
  __syncthreads();

  // ---- fc1 partial: C[16n x 64k] over m in [0,2048), wave w owns m-chunk 512
  f32x4 facc[4];
#pragma unroll
  for (int cb = 0; cb < 4; ++cb) {
    facc[cb][0] = 0.f; facc[cb][1] = 0.f; facc[cb][2] = 0.f; facc[cb][3] = 0.f;
  }
  const unsigned short* bp =
      w1b + (long)c0 * KTOT + h * 4096 + ih * 2048 + w * 512 + ks * 8;
  const unsigned short* ap = &att_s[0][0] + c0 * PADM + w * 512 + ks * 8;
  short8 zero8;
#pragma unroll
  for (int e = 0; e < 8; ++e) zero8[e] = 0;
#pragma unroll 4
  for (int s = 0; s < 16; ++s) {
    short8 a = (c0 < 8) ? *(const short8*)(ap + s * 32) : zero8;
#pragma unroll
    for (int cb = 0; cb < 4; ++cb) {
      short8 b = *(const short8*)(bp + (long)cb * 16 * KTOT + s * 32);
      facc[cb] = __builtin_amdgcn_mfma_f32_16x16x32_bf16(a, b, facc[cb], 0, 0, 0);
    }
  }
  // ---- cross-wave reduce (valid C rows = ks*4+r in 0..7 i.e. ks<2)
  if (ks < 2) {
#pragma unroll
    for (int cb = 0; cb < 4; ++cb)
#pragma unroll
      for (int r = 0; r < 4; ++r)
        red[w][ks * 4 + r][c0 + 16 * cb] = facc[cb][r];
  }
  __syncthreads();
#pragma unroll
  for (int rep = 0; rep < 2; ++rep) {
    int e = tid + rep * 256;
    int nl = e >> 6, k = e & 63;
    float s = red[0][nl][k] + red[1][nl][k] + red[2][nl][k] + red[3][nl][k];
    partial[(((long)h * 2 + ih) * 256 + ng * 8 + nl) * 64 + k] = s;
  }
}

// ---------------- K2: reduce 16 partials + bias + silu + fc2 ----------------
__global__ __launch_bounds__(256)
void k_fc2(const float* __restrict__ partial, const float* __restrict__ fc1_b,
           const float* __restrict__ fc2_w, const float* __restrict__ fc2_b,
           float* __restrict__ out) {
  const int tid = threadIdx.x;
  const int n = blockIdx.x * 4 + (tid >> 6);
  const int k = tid & 63;
  float s = fc1_b[k];
#pragma unroll
  for (int sp = 0; sp < 16; ++sp)
    s += partial[((long)sp * 256 + n) * 64 + k];
  float g = s / (1.f + __expf(-s));   // silu
  float v = g * fc2_w[k];
#pragma unroll
  for (int off = 32; off > 0; off >>= 1)
    v += __shfl_xor(v, off, 64);
  if (k == 0) out[n] = v + fc2_b[0];
}

extern "C" void kernel_launch(void* const* d_in, const int* in_sizes, int n_in,
                              void* d_out, int out_size, void* d_ws, size_t ws_size,
                              hipStream_t stream) {
  const float* X    = (const float*)d_in[0];
  const float* Wl   = (const float*)d_in[1];
  const float* Wr   = (const float*)d_in[2];
  const float* fc1w = (const float*)d_in[3];
  const float* fc1b = (const float*)d_in[4];
  const float* fc2w = (const float*)d_in[5];
  const float* fc2b = (const float*)d_in[6];
  float* out = (float*)d_out;

  char* ws = (char*)d_ws;
  unsigned short* w1b     = (unsigned short*)(ws);             // 4,194,304 B
  float*          partial = (float*)(ws + 4194304);            // 1,048,576 B

  hipLaunchKernelGGL(k_cvt_w, dim3(2048), dim3(256), 0, stream, fc1w, w1b);
  hipLaunchKernelGGL(k_fused, dim3(512), dim3(256), 0, stream, X, Wl, Wr, w1b, partial);
  hipLaunchKernelGGL(k_fc2,   dim3(64), dim3(256), 0, stream, partial, fc1b, fc2w, fc2b, out);
}

// Round 4
// 39.458 us; speedup vs baseline: 1.3186x; 1.0451x over previous
//
#include <hip/hip_runtime.h>
#include <hip/hip_bf16.h>

// Outer_14173392076867 — fused pipeline v3b, MI355X gfx950.
// K0: fc1_w f32->bf16 (k-major [64][32768]) into ws
// K1: fused per-(ih,h,ng16): dX -> att (LDS, 16 n) -> fc1 partial GEMM with
//     full 16-row MFMA A-frags, w1b streamed from same-XCD L2 (16 rereads).
// K2: reduce 16 partials + bias + silu + fc2 -> out[256]

typedef __attribute__((ext_vector_type(8))) short short8;
typedef __attribute__((ext_vector_type(4))) float f32x4;
typedef __attribute__((ext_vector_type(4))) unsigned short u16x4;

#define PADW 72      // LDS row pad (ushorts): 144B rows, 16B aligned, 2-way banks
#define PADM 2056    // att row: 2048 + 8 ushorts -> 4112B rows
#define KTOT 32768L

__device__ __forceinline__ unsigned short f2b(float x) {
  union { float f; unsigned int u; } v; v.f = x;
  return (unsigned short)((v.u + 0x7FFFu + ((v.u >> 16) & 1u)) >> 16);
}

// packed f32x2 -> bf16x2 (round-to-nearest-even), single v_cvt_pk_bf16_f32
__device__ __forceinline__ unsigned int pk_bf16(float lo, float hi) {
  unsigned int r;
  asm("v_cvt_pk_bf16_f32 %0, %1, %2" : "=v"(r) : "v"(lo), "v"(hi));
  return r;
}

// ---------------- K0: convert fc1_w (2,097,152 f32) to bf16 ----------------
__global__ __launch_bounds__(256)
void k_cvt_w(const float* __restrict__ in, unsigned short* __restrict__ out) {
  const int i = (blockIdx.x * 256 + threadIdx.x) * 4;
  f32x4 v = *(const f32x4*)(in + i);
  u16x4 o;
#pragma unroll
  for (int e = 0; e < 4; ++e) o[e] = f2b(v[e]);
  *(u16x4*)(out + i) = o;
}

// ---------------- K1: fused dX -> att (LDS) -> fc1 partial ----------------
// grid = 256: ih = blk&1, h = (blk>>1)&7, ng = blk>>4 (16 n's per block).
// block = 512 (8 waves). Phase A: 8 double-q iterations (2 q in flight).
// Wave w in att MFMA: qsub = w>>2, iw = (w>>1)&1 (16-row i-sub), dw = w&1.
// Phase B: wave w owns m-chunk of 256; 16-row A-frags (no zero padding).
__global__ __launch_bounds__(512, 1)
void k_fused(const float* __restrict__ X, const float* __restrict__ Wl_g,
             const float* __restrict__ Wr_g,
             const unsigned short* __restrict__ w1b,
             float* __restrict__ partial) {
  __shared__ float xs[16][3][64];                              // 12288 B
  __shared__ __align__(16) union {
    struct {
      unsigned short wl[64][PADW];                             //  9216 B
      unsigned short wr[64][PADW];                             //  9216 B
      unsigned short dxs[2][3][32][PADW];                      // 27648 B
    } a;
    float red[8][16][64];                                      // 32768 B
  } u;                                                         // 46080 B
  __shared__ __align__(16) unsigned short att_s[16][PADM];     // 65792 B => 124160 B

  const int blk  = blockIdx.x;
  const int ih   = blk & 1;
  const int h    = (blk >> 1) & 7;
  const int ng   = blk >> 4;
  const int tid  = threadIdx.x;
  const int lane = tid & 63;
  const int w    = tid >> 6;
  const int c0   = lane & 15;
  const int ks   = lane >> 4;
  const int iw   = (w >> 1) & 1;
  const int dw   = w & 1;
  const int qsub = w >> 2;           // which of the 2 in-flight q's this wave MFMAs

  // ---- W slices (per h): coalesced f32 read, transposed bf16 store [d][j]
  const float* wlg = Wl_g + h * 4096;
  const float* wrg = Wr_g + h * 4096;
#pragma unroll
  for (int r = 0; r < 8; ++r) {
    int e = tid + r * 512;
    int j = e >> 6, d = e & 63;
    u.a.wl[d][j] = f2b(wlg[e]);
    u.a.wr[d][j] = f2b(wrg[e]);
  }
  // ---- X for 16 n: [q][t][i] (3072 floats, coalesced)
  {
    const long xbase = ((long)(ng * 16) * 8 + h) * 192;
#pragma unroll
    for (int r = 0; r < 6; ++r) {
      int e = tid + r * 512;
      int q = e / 192;
      int rem = e - q * 192;
      int i = rem / 3;
      int t = rem - i * 3;
      xs[q][t][i] = X[xbase + (long)q * 1536 + rem];
    }
  }
  __syncthreads();

  // ---- B fragments for the att GEMM (this wave's d-half), t-invariant
  short8 bl[2][2], br[2][2];
#pragma unroll
  for (int cb = 0; cb < 2; ++cb)
#pragma unroll
    for (int kb = 0; kb < 2; ++kb) {
      const int d = c0 + 16 * cb + 32 * dw;
      const int j0 = ks * 8 + 32 * kb;
      bl[cb][kb] = *(const short8*)&u.a.wl[d][j0];
      br[cb][kb] = *(const short8*)&u.a.wr[d][j0];
    }

  const int dq  = tid >> 8;          // dX sub-buffer this thread fills (0/1)
  const int il  = (tid >> 3) & 31;   // dX row (local, 0..31)
  const int jb  = (tid & 7) << 3;    // 8-col chunk

  for (int it = 0; it < 8; ++it) {
    const int qd = it * 2 + dq;      // q this thread computes dX for
    if (it) __syncthreads();         // dxs overwrite vs prev A-reads
    // dX[i = ih*32+il][j], 3 t's, 8 j's per thread
#pragma unroll
    for (int t = 0; t < 3; ++t) {
      const float xi = xs[qd][t][ih * 32 + il];
#pragma unroll
      for (int jj = 0; jj < 8; jj += 2) {
        float d0 = xi - xs[qd][t][jb + jj];
        float d1 = xi - xs[qd][t][jb + jj + 1];
        float s0 = d0 * d0 + 1e-5f;
        float s1 = d1 * d1 + 1e-5f;
        float i0 = rsqrtf(s0), i1 = rsqrtf(s1);
        float e0 = __expf(-(s0 * i0));
        float e1 = __expf(-(s1 * i1));
        *(unsigned int*)&u.a.dxs[dq][t][il][jb + jj] =
            pk_bf16(d0 * i0 * e0, d1 * i1 * e1);
      }
    }
    __syncthreads();

    // att tile for q = it*2 + qsub: wave computes [16 i x 32 d], K=64 over j
    const int q = it * 2 + qsub;
    f32x4 acc[2];
#pragma unroll
    for (int cb = 0; cb < 2; ++cb) {
      acc[cb][0] = 0.f; acc[cb][1] = 0.f; acc[cb][2] = 0.f; acc[cb][3] = 0.f;
    }
#pragma unroll
    for (int t = 0; t < 3; ++t) {
      short8 a0 = *(const short8*)&u.a.dxs[qsub][t][iw * 16 + c0][ks * 8];
      short8 a1 = *(const short8*)&u.a.dxs[qsub][t][iw * 16 + c0][ks * 8 + 32];
#pragma unroll
      for (int cb = 0; cb < 2; ++cb) {
        f32x4 xl; xl[0]=0.f; xl[1]=0.f; xl[2]=0.f; xl[3]=0.f;
        f32x4 xr; xr[0]=0.f; xr[1]=0.f; xr[2]=0.f; xr[3]=0.f;
        xl = __builtin_amdgcn_mfma_f32_16x16x32_bf16(a0, bl[cb][0], xl, 0, 0, 0);
        xl = __builtin_amdgcn_mfma_f32_16x16x32_bf16(a1, bl[cb][1], xl, 0, 0, 0);
        xr = __builtin_amdgcn_mfma_f32_16x16x32_bf16(a0, br[cb][0], xr, 0, 0, 0);
        xr = __builtin_amdgcn_mfma_f32_16x16x32_bf16(a1, br[cb][1], xr, 0, 0, 0);
        acc[cb] += xl * xr;
      }
    }
    // store bf16 att tile: m-local = row*64 + d
#pragma unroll
    for (int cb = 0; cb < 2; ++cb)
#pragma unroll
      for (int r = 0; r < 4; ++r) {
        int ro = iw * 16 + ks * 4 + r;
        int d = c0 + 16 * cb + 32 * dw;
        att_s[q][ro * 64 + d] = f2b(acc[cb][r]);
      }
  }
  __syncthreads();

  // ---- fc1 partial: C[16n x 64k], m in [0,2048), wave w owns m-chunk 256
  f32x4 facc[4];
#pragma unroll
  for (int cb = 0; cb < 4; ++cb) {
    facc[cb][0] = 0.f; facc[cb][1] = 0.f; facc[cb][2] = 0.f; facc[cb][3] = 0.f;
  }
  const unsigned short* bp =
      w1b + (long)c0 * KTOT + h * 4096 + ih * 2048 + w * 256 + ks * 8;
  const unsigned short* ap = &att_s[0][0] + c0 * PADM + w * 256 + ks * 8;
#pragma unroll
  for (int s = 0; s < 8; ++s) {
    short8 a = *(const short8*)(ap + s * 32);
#pragma unroll
    for (int cb = 0; cb < 4; ++cb) {
      short8 b = *(const short8*)(bp + (long)cb * 16 * KTOT + s * 32);
      facc[cb] = __builtin_amdgcn_mfma_f32_16x16x32_bf16(a, b, facc[cb], 0, 0, 0);
    }
  }
  __syncthreads();                   // att_s/u reads done; u.red reuse
  // ---- cross-wave reduce: C rows = ks*4+r (0..15), cols = c0+16cb
#pragma unroll
  for (int cb = 0; cb < 4; ++cb)
#pragma unroll
    for (int r = 0; r < 4; ++r)
      u.red[w][ks * 4 + r][c0 + 16 * cb] = facc[cb][r];
  __syncthreads();
#pragma unroll
  for (int rep = 0; rep < 2; ++rep) {
    int e = tid + rep * 512;
    int nl = e >> 6, k = e & 63;
    float s = 0.f;
#pragma unroll
    for (int ww = 0; ww < 8; ++ww) s += u.red[ww][nl][k];
    partial[(((long)h * 2 + ih) * 256 + ng * 16 + nl) * 64 + k] = s;
  }
}

// ---------------- K2: reduce 16 partials + bias + silu + fc2 ----------------
__global__ __launch_bounds__(256)
void k_fc2(const float* __restrict__ partial, const float* __restrict__ fc1_b,
           const float* __restrict__ fc2_w, const float* __restrict__ fc2_b,
           float* __restrict__ out) {
  const int tid = threadIdx.x;
  const int n = blockIdx.x * 4 + (tid >> 6);
  const int k = tid & 63;
  float s = fc1_b[k];
#pragma unroll
  for (int sp = 0; sp < 16; ++sp)
    s += partial[((long)sp * 256 + n) * 64 + k];
  float g = s / (1.f + __expf(-s));   // silu
  float v = g * fc2_w[k];
#pragma unroll
  for (int off = 32; off > 0; off >>= 1)
    v += __shfl_xor(v, off, 64);
  if (k == 0) out[n] = v + fc2_b[0];
}

extern "C" void kernel_launch(void* const* d_in, const int* in_sizes, int n_in,
                              void* d_out, int out_size, void* d_ws, size_t ws_size,
                              hipStream_t stream) {
  const float* X    = (const float*)d_in[0];
  const float* Wl   = (const float*)d_in[1];
  const float* Wr   = (const float*)d_in[2];
  const float* fc1w = (const float*)d_in[3];
  const float* fc1b = (const float*)d_in[4];
  const float* fc2w = (const float*)d_in[5];
  const float* fc2b = (const float*)d_in[6];
  float* out = (float*)d_out;

  char* ws = (char*)d_ws;
  unsigned short* w1b     = (unsigned short*)(ws);             // 4,194,304 B
  float*          partial = (float*)(ws + 4194304);            // 1,048,576 B

  hipLaunchKernelGGL(k_cvt_w, dim3(2048), dim3(256), 0, stream, fc1w, w1b);
  hipLaunchKernelGGL(k_fused, dim3(256), dim3(512), 0, stream, X, Wl, Wr, w1b, partial);
  hipLaunchKernelGGL(k_fc2,   dim3(64), dim3(256), 0, stream, partial, fc1b, fc2w, fc2b, out);
}